// Round 8
// baseline (454.453 us; speedup 1.0000x reference)
//
#include <hip/hip_runtime.h>

// Problem constants
constexpr int cB   = 2;
constexpr int cS   = 2048;
constexpr int cH   = 2048;
constexpr int cNH  = 16;
constexpr int cKVH = 4;
constexpr int cHD  = 128;
constexpr int cQD  = 2048;   // NH*HD
constexpr int cKVD = 512;    // KVH*HD
constexpr int cNQKV = 3072;  // QD + 2*KVD
constexpr int cNTOK = 4096;  // B*S
#define ATTN_SCALE 0.08838834764831845f
// ATTN_SCALE * log2(e): Q pre-scaled so softmax runs in exp2 domain
#define QSCALE 0.12751589549581288f

typedef __bf16 bf16;
typedef __attribute__((ext_vector_type(8))) __bf16 bf16x8;
typedef __attribute__((ext_vector_type(4))) __bf16 bf16x4;
typedef __attribute__((ext_vector_type(4))) float  f32x4;

__device__ __forceinline__ void async_load16(const bf16* g, bf16* l) {
    __builtin_amdgcn_global_load_lds(
        (const __attribute__((address_space(1))) void*)g,
        (__attribute__((address_space(3))) void*)l, 16, 0, 0);
}

// ---------------- fused prep: x->bf16, ow->bf16, LoRA-folded QKV weight (1 kernel, 3 jobs) ----------
__global__ __launch_bounds__(256) void prep_all(
        const float* __restrict__ x, bf16* __restrict__ Xbf,
        const float* __restrict__ ow, bf16* __restrict__ OWbf,
        const float* __restrict__ qw, const float* __restrict__ kw, const float* __restrict__ vw,
        const float* __restrict__ qA, const float* __restrict__ qB,
        const float* __restrict__ kA, const float* __restrict__ kB,
        const float* __restrict__ vA, const float* __restrict__ vB,
        const float* __restrict__ qb, const float* __restrict__ kbias, const float* __restrict__ vb,
        bf16* __restrict__ Wc, float* __restrict__ biasc) {
    const int bid = blockIdx.x;
    if (bid < 8192) {                    // x -> Xbf
        const int i = (bid * 256 + threadIdx.x) * 4;
        f32x4 v = *(const f32x4*)(x + i);
        bf16x4 o;
        o[0] = (bf16)v[0]; o[1] = (bf16)v[1]; o[2] = (bf16)v[2]; o[3] = (bf16)v[3];
        *(bf16x4*)(Xbf + i) = o;
        return;
    }
    if (bid < 12288) {                   // ow -> OWbf
        const int i = ((bid - 8192) * 256 + threadIdx.x) * 4;
        f32x4 v = *(const f32x4*)(ow + i);
        bf16x4 o;
        o[0] = (bf16)v[0]; o[1] = (bf16)v[1]; o[2] = (bf16)v[2]; o[3] = (bf16)v[3];
        *(bf16x4*)(OWbf + i) = o;
        return;
    }
    // LoRA fold
    const int pb = bid - 12288;
    const int bx = pb & 3, by = pb >> 2;
    const int wave = threadIdx.x >> 6, lane = threadIdx.x & 63;
    const int n = by * 4 + wave;
    const int k0 = bx * 512 + lane * 8;
    const float* W; const float* Am; const float* Bm; const float* bias; int nn, nd;
    if (n < cQD)             { W = qw; Am = qA; Bm = qB; bias = qb;    nn = n;               nd = cQD; }
    else if (n < cQD + cKVD) { W = kw; Am = kA; Bm = kB; bias = kbias; nn = n - cQD;         nd = cKVD; }
    else                     { W = vw; Am = vA; Bm = vB; bias = vb;    nn = n - cQD - cKVD;  nd = cKVD; }
    if (bx == 0 && lane == 0) biasc[n] = bias[nn];
    float bm[16];
    #pragma unroll
    for (int r = 0; r < 16; ++r) bm[r] = Bm[r * nd + nn];
    const float* wrow = W + (size_t)nn * cH + k0;
    f32x4 w0 = *(const f32x4*)(wrow);
    f32x4 w1 = *(const f32x4*)(wrow + 4);
    bf16x8 o;
    #pragma unroll
    for (int j = 0; j < 8; ++j) {
        const f32x4* am = (const f32x4*)(Am + (size_t)(k0 + j) * 16);
        f32x4 a0 = am[0], a1 = am[1], a2 = am[2], a3 = am[3];
        float acc = 0.f;
        #pragma unroll
        for (int c = 0; c < 4; ++c) acc += a0[c] * bm[c] + a1[c] * bm[4 + c]
                                         + a2[c] * bm[8 + c] + a3[c] * bm[12 + c];
        const float wv = (j < 4) ? w0[j] : w1[j - 4];
        o[j] = (bf16)(wv + 2.0f * acc);
    }
    *(bf16x8*)&Wc[(size_t)n * cH + k0] = o;
}

// ---------------- QKV GEMM v5 (round-7 verified, unchanged control) ----------------
__global__ __launch_bounds__(256, 2) void gemm_qkv5(const bf16* __restrict__ A, const bf16* __restrict__ Bw,
                                                    const float* __restrict__ bias,
                                                    const float* __restrict__ cosb, const float* __restrict__ sinb,
                                                    bf16* __restrict__ Qr, bf16* __restrict__ Kr,
                                                    bf16* __restrict__ Vt) {
    __shared__ bf16 Al[128 * 128];   // 32 KiB
    __shared__ bf16 Bl[128 * 128];   // 32 KiB -> 64 KiB total
    const int tid = threadIdx.x;
    const int wave = tid >> 6, lane = tid & 63;
    const int quad = lane >> 4, l16 = lane & 15;
    const int wr = wave >> 1, wc = wave & 1;
    const int K = cH;
    constexpr int GX = cNQKV / 128;            // 24
    constexpr int NWG = GX * (cNTOK / 128);    // 768, %8==0 -> bijective XCD swizzle

    const int orig = blockIdx.y * GX + blockIdx.x;
    const int swz = (orig & 7) * (NWG >> 3) + (orig >> 3);
    const long bm = (long)(swz / GX) * 128;
    const long bn = (long)(swz % GX) * 128;

    f32x4 acc[4][4];
    #pragma unroll
    for (int i = 0; i < 4; ++i)
        #pragma unroll
        for (int c = 0; c < 4; ++c) acc[i][c] = f32x4{0.f, 0.f, 0.f, 0.f};

    int ago[8], slo[8];
    #pragma unroll
    for (int i2 = 0; i2 < 8; ++i2) {
        const int si = i2 * 256 + tid;
        const int row = si >> 4, c16 = si & 15;
        const int csw = (c16 & 8) | ((c16 & 7) ^ (row & 7));
        ago[i2] = row * K + csw * 8;
        slo[i2] = si * 8;
    }
    const size_t bmK = (size_t)bm * K, bnK = (size_t)bn * K;

    auto STAGE = [&](int tt) {
        const bf16* As_ = A  + bmK + (size_t)tt * 128;
        const bf16* Bs_ = Bw + bnK + (size_t)tt * 128;
        #pragma unroll
        for (int i2 = 0; i2 < 8; ++i2) {
            async_load16(As_ + ago[i2], &Al[slo[i2]]);
            async_load16(Bs_ + ago[i2], &Bl[slo[i2]]);
        }
    };

    constexpr int NT = cH / 128;   // 16
    STAGE(0);
    const int sw = l16 & 7;

    for (int t = 0; t < NT; ++t) {
        asm volatile("s_waitcnt vmcnt(0)" ::: "memory");
        __builtin_amdgcn_s_barrier();
        #pragma unroll
        for (int ks = 0; ks < 4; ++ks) {
            const int g = ks * 4 + quad;          // chunk 0..15
            const int gsw = (g & 8) | ((g & 7) ^ sw);
            const int cofs = gsw * 8;
            bf16x8 af[4], bfr[4];
            #pragma unroll
            for (int i = 0; i < 4; ++i)
                af[i] = *(const bf16x8*)&Al[(wr * 64 + i * 16 + l16) * 128 + cofs];
            #pragma unroll
            for (int c = 0; c < 4; ++c) {
                const int nrow = wc * 32 + (c & 1) * 16 + (c >> 1) * 64 + l16;
                bfr[c] = *(const bf16x8*)&Bl[nrow * 128 + cofs];
            }
            __builtin_amdgcn_s_setprio(1);
            #pragma unroll
            for (int i = 0; i < 4; ++i)
                #pragma unroll
                for (int c = 0; c < 4; ++c)
                    acc[i][c] = __builtin_amdgcn_mfma_f32_16x16x32_bf16(af[i], bfr[c], acc[i][c], 0, 0, 0);
            __builtin_amdgcn_s_setprio(0);
        }
        asm volatile("s_waitcnt lgkmcnt(0)" ::: "memory");
        __builtin_amdgcn_s_barrier();
        if (t + 1 < NT) STAGE(t + 1);
    }

    // ---- epilogue (verified): bias + RoPE + reorder + V-transpose ----
    #pragma unroll
    for (int c = 0; c < 4; ++c) {
        const int nloc = wc * 32 + (c & 1) * 16 + (c >> 1) * 64 + l16;
        const float bv = bias[bn + nloc];
        #pragma unroll
        for (int i = 0; i < 4; ++i)
            #pragma unroll
            for (int r = 0; r < 4; ++r) acc[i][c][r] += bv;
    }

    const int head = (int)(bn >> 7);   // 0..23: 16 Q, 4 K, 4 V
    if (head < cNH + cKVH) {
        const bool isQ = head < cNH;
        #pragma unroll
        for (int cl = 0; cl < 2; ++cl) {
            const int d = wc * 32 + cl * 16 + l16;   // 0..63
            #pragma unroll
            for (int i = 0; i < 4; ++i)
                #pragma unroll
                for (int r = 0; r < 4; ++r) {
                    const long t = bm + wr * 64 + i * 16 + quad * 4 + r;
                    const float cv = cosb[t * cHD + d];
                    const float sv = sinb[t * cHD + d];
                    const float v1 = acc[i][cl][r], v2 = acc[i][cl + 2][r];
                    float o1 = v1 * cv - v2 * sv;
                    float o2 = v2 * cv + v1 * sv;
                    if (isQ) { o1 *= QSCALE; o2 *= QSCALE; }
                    const int b = (int)(t >> 11), s = (int)(t & 2047);
                    bf16* dst = isQ
                        ? Qr + ((size_t)(b * cNH + head) * cS + s) * cHD
                        : Kr + ((size_t)(b * cKVH + (head - cNH)) * cS + s) * cHD;
                    dst[d]      = (bf16)o1;
                    dst[d + 64] = (bf16)o2;
                }
        }
    } else {
        const int kv = head - cNH - cKVH;
        const int b = (int)(bm >> 11);
        const int sbase = (int)(bm & 2047);
        #pragma unroll
        for (int c = 0; c < 4; ++c) {
            const int d = wc * 32 + (c & 1) * 16 + (c >> 1) * 64 + l16;
            #pragma unroll
            for (int i = 0; i < 4; ++i) {
                const int s0 = sbase + wr * 64 + i * 16 + quad * 4;
                bf16x4 o4;
                #pragma unroll
                for (int r = 0; r < 4; ++r) o4[r] = (bf16)acc[i][c][r];
                *(bf16x4*)&Vt[((size_t)((b * cKVH + kv) * cHD) + d) * cS + s0] = o4;
            }
        }
    }
}

// ---------------- o-proj GEMM v5 (round-7 verified, unchanged) ----------------
__global__ __launch_bounds__(256, 2) void gemm_oproj5(const bf16* __restrict__ A, const bf16* __restrict__ Bw,
                                                      float* __restrict__ Cp) {
    __shared__ bf16 Al[128 * 128];   // 32 KiB
    __shared__ bf16 Bl[128 * 128];   // 32 KiB
    const int tid = threadIdx.x;
    const int wave = tid >> 6, lane = tid & 63;
    const int quad = lane >> 4, l16 = lane & 15;
    const int wr = wave >> 1, wc = wave & 1;
    constexpr int K = cH, N = cH;
    constexpr int GX = cH / 128;               // 16
    constexpr int NWG = GX * (cNTOK / 128);    // 512, %8==0

    const int orig = blockIdx.y * GX + blockIdx.x;
    const int swz = (orig & 7) * (NWG >> 3) + (orig >> 3);
    const long bm = (long)(swz / GX) * 128;
    const long bn = (long)(swz % GX) * 128;

    f32x4 acc[4][4];
    #pragma unroll
    for (int i = 0; i < 4; ++i)
        #pragma unroll
        for (int c = 0; c < 4; ++c) acc[i][c] = f32x4{0.f, 0.f, 0.f, 0.f};

    int ago[8], slo[8];
    #pragma unroll
    for (int i2 = 0; i2 < 8; ++i2) {
        const int si = i2 * 256 + tid;
        const int row = si >> 4, c16 = si & 15;
        const int csw = (c16 & 8) | ((c16 & 7) ^ (row & 7));
        ago[i2] = row * K + csw * 8;
        slo[i2] = si * 8;
    }
    const size_t bmK = (size_t)bm * K, bnK = (size_t)bn * K;

    auto STAGE = [&](int tt) {
        const bf16* As_ = A  + bmK + (size_t)tt * 128;
        const bf16* Bs_ = Bw + bnK + (size_t)tt * 128;
        #pragma unroll
        for (int i2 = 0; i2 < 8; ++i2) {
            async_load16(As_ + ago[i2], &Al[slo[i2]]);
            async_load16(Bs_ + ago[i2], &Bl[slo[i2]]);
        }
    };

    constexpr int NT = K / 128;   // 16
    STAGE(0);
    const int sw = l16 & 7;

    for (int t = 0; t < NT; ++t) {
        asm volatile("s_waitcnt vmcnt(0)" ::: "memory");
        __builtin_amdgcn_s_barrier();
        #pragma unroll
        for (int ks = 0; ks < 4; ++ks) {
            const int g = ks * 4 + quad;
            const int gsw = (g & 8) | ((g & 7) ^ sw);
            const int cofs = gsw * 8;
            bf16x8 af[4], bfr[4];
            #pragma unroll
            for (int i = 0; i < 4; ++i)
                af[i] = *(const bf16x8*)&Al[(wr * 64 + i * 16 + l16) * 128 + cofs];
            #pragma unroll
            for (int c = 0; c < 4; ++c)
                bfr[c] = *(const bf16x8*)&Bl[(wc * 64 + c * 16 + l16) * 128 + cofs];
            __builtin_amdgcn_s_setprio(1);
            #pragma unroll
            for (int i = 0; i < 4; ++i)
                #pragma unroll
                for (int c = 0; c < 4; ++c)
                    acc[i][c] = __builtin_amdgcn_mfma_f32_16x16x32_bf16(af[i], bfr[c], acc[i][c], 0, 0, 0);
            __builtin_amdgcn_s_setprio(0);
        }
        asm volatile("s_waitcnt lgkmcnt(0)" ::: "memory");
        __builtin_amdgcn_s_barrier();
        if (t + 1 < NT) STAGE(t + 1);
    }

    #pragma unroll
    for (int i = 0; i < 4; ++i)
        #pragma unroll
        for (int c = 0; c < 4; ++c) {
            const long m0 = bm + wr * 64 + i * 16 + quad * 4;
            const long n  = bn + wc * 64 + c * 16 + l16;
            #pragma unroll
            for (int r = 0; r < 4; ++r)
                Cp[(m0 + r) * N + n] = acc[i][c][r];
        }
}

// ---------------- flash attention v7: K staged in LDS, V DIRECT from global (L2-resident) ----------
// m169 principle: don't stage what the cache serves. Vt is d-major so V^T fragments are natural
// contiguous global reads (64B per quad-group); each (b,kvh) V panel (512 KB) is shared by 64
// blocks -> L2-hot. Halves the global_load_lds staging-path bytes (the measured bottleneck).
__global__ __launch_bounds__(256, 2) void flash7(const bf16* __restrict__ Q, const bf16* __restrict__ K,
                                                 const bf16* __restrict__ Vt, bf16* __restrict__ Ob) {
    __shared__ bf16 kb[128 * 128];   // 32 KiB  (kpos rows x d cols)
    __shared__ bf16 pb[4 * 2048];    // 16 KiB -> 48 KiB total, 2 blocks/CU
    const int tid = threadIdx.x;
    const int wave = tid >> 6, lane = tid & 63;
    const int quad = lane >> 4, l16 = lane & 15;
    const int pi = blockIdx.x;               // 0..15
    const int h = blockIdx.y, b = blockIdx.z;

    const bf16* Qh = Q  + (size_t)(b * cNH + h) * cS * cHD;
    const bf16* Kg = K  + (size_t)(b * cKVH + (h >> 2)) * cS * cHD;
    const bf16* Vg = Vt + (size_t)(b * cKVH + (h >> 2)) * cHD * cS;

    int kgo[8], slo[8];
    #pragma unroll
    for (int i2 = 0; i2 < 8; ++i2) {
        const int si = i2 * 256 + tid;       // 0..2047
        const int row = si >> 4, c16 = si & 15;
        const int csw = (c16 & 8) | ((c16 & 7) ^ (row & 7));
        kgo[i2] = row * cHD + csw * 8;       // K: kpos-row x d-chunk
        slo[i2] = si * 8;
    }

    #pragma unroll
    for (int t2 = 0; t2 < 2; ++t2) {
        const int qt = t2 == 0 ? (31 - pi) : pi;

        const bf16* Qg = Qh + (size_t)qt * 64 * cHD;
        bf16x8 qf[4];
        #pragma unroll
        for (int ks = 0; ks < 4; ++ks)
            qf[ks] = *(const bf16x8*)(Qg + (size_t)(wave * 16 + l16) * cHD + ks * 32 + quad * 8);

        f32x4 oac[8];
        #pragma unroll
        for (int dt = 0; dt < 8; ++dt) oac[dt] = f32x4{0.f, 0.f, 0.f, 0.f};
        float m_ = -3.0e38f, l_ = 0.f;

        const int nkt = (qt >> 1) + 1;       // 128-wide tiles covering [0, qt*64+63]
        for (int kt = 0; kt < nkt; ++kt) {
            __syncthreads();                 // prior-step kb reads sealed before overwrite
            const bf16* Kt  = Kg + (size_t)kt * 128 * cHD;
            const bf16* Vtt = Vg + kt * 128;
            #pragma unroll
            for (int i2 = 0; i2 < 8; ++i2) async_load16(Kt + kgo[i2], kb + slo[i2]);
            __syncthreads();                 // drains vmcnt(0): K tile visible

            // S^T = K Q^T : st[mt] rows = kpos (mt*16+quad*4+r), cols = q (l16)
            f32x4 st[8];
            #pragma unroll
            for (int mt = 0; mt < 8; ++mt) {
                bf16x8 kf[4];
                #pragma unroll
                for (int ks = 0; ks < 4; ++ks) {
                    const int c = ks * 4 + quad;
                    const int csw = (c & 8) | ((c & 7) ^ (l16 & 7));
                    kf[ks] = *(const bf16x8*)&kb[(mt * 16 + l16) * 128 + csw * 8];
                }
                f32x4 a = f32x4{0.f, 0.f, 0.f, 0.f};
                __builtin_amdgcn_s_setprio(1);
                #pragma unroll
                for (int ks = 0; ks < 4; ++ks)
                    a = __builtin_amdgcn_mfma_f32_16x16x32_bf16(kf[ks], qf[ks], a, 0, 0, 0);
                __builtin_amdgcn_s_setprio(0);
                st[mt] = a;
            }

            // causal mask + online softmax (exp2 domain; lane l16 = q row)
            const int qpos = qt * 64 + wave * 16 + l16;
            float tmax = -3.0e38f;
            if ((kt * 128 + 127) > (qt * 64 + wave * 16)) {
                #pragma unroll
                for (int mt = 0; mt < 8; ++mt)
                    #pragma unroll
                    for (int r = 0; r < 4; ++r) {
                        const int kpos = kt * 128 + mt * 16 + quad * 4 + r;
                        if (kpos > qpos) st[mt][r] = -3.0e38f;
                        tmax = fmaxf(tmax, st[mt][r]);
                    }
            } else {
                #pragma unroll
                for (int mt = 0; mt < 8; ++mt)
                    #pragma unroll
                    for (int r = 0; r < 4; ++r) tmax = fmaxf(tmax, st[mt][r]);
            }
            tmax = fmaxf(tmax, __shfl_xor(tmax, 16, 64));
            tmax = fmaxf(tmax, __shfl_xor(tmax, 32, 64));
            const float mnew = fmaxf(m_, tmax);
            if (__any(tmax > m_)) {
                const float alpha = __builtin_amdgcn_exp2f(m_ - mnew);
                l_ *= alpha;
                #pragma unroll
                for (int dt = 0; dt < 8; ++dt)
                    #pragma unroll
                    for (int r = 0; r < 4; ++r) oac[dt][r] *= alpha;
            }
            m_ = mnew;
            float rs = 0.f;
            #pragma unroll
            for (int mt = 0; mt < 8; ++mt)
                #pragma unroll
                for (int r = 0; r < 4; ++r) {
                    const float p = __builtin_amdgcn_exp2f(st[mt][r] - mnew);
                    st[mt][r] = p;
                    rs += p;
                }
            rs += __shfl_xor(rs, 16, 64);
            rs += __shfl_xor(rs, 32, 64);
            l_ += rs;

            // P write into per-wave pb region (wave-private, no barrier)
            #pragma unroll
            for (int mt = 0; mt < 8; ++mt) {
                bf16x4 p4;
                #pragma unroll
                for (int r = 0; r < 4; ++r) p4[r] = (bf16)st[mt][r];
                const int c16 = mt * 2 + (quad >> 1);
                const int csw = (c16 & 8) | ((c16 & 7) ^ (l16 & 7));
                *(bf16x4*)&pb[wave * 2048 + l16 * 128 + csw * 8 + (quad & 1) * 4] = p4;
            }

            // O^T += V^T P^T  (V fragments DIRECT from global Vt: row d, cols kt*128..)
            bf16x8 pf[4];
            #pragma unroll
            for (int ks = 0; ks < 4; ++ks) {
                const int c = ks * 4 + quad;
                const int csw = (c & 8) | ((c & 7) ^ (l16 & 7));
                pf[ks] = *(const bf16x8*)&pb[wave * 2048 + l16 * 128 + csw * 8];
            }
            #pragma unroll
            for (int dt = 0; dt < 8; ++dt) {
                const bf16* vrow = Vtt + (size_t)(dt * 16 + l16) * cS;
                bf16x8 vf[4];
                #pragma unroll
                for (int ks = 0; ks < 4; ++ks)
                    vf[ks] = *(const bf16x8*)(vrow + (ks * 4 + quad) * 8);
                __builtin_amdgcn_s_setprio(1);
                #pragma unroll
                for (int ks = 0; ks < 4; ++ks)
                    oac[dt] = __builtin_amdgcn_mfma_f32_16x16x32_bf16(vf[ks], pf[ks], oac[dt], 0, 0, 0);
                __builtin_amdgcn_s_setprio(0);
            }
        }

        // epilogue: lane l16 = token, regs = d contiguous -> b64 stores
        const float inv = 1.0f / l_;
        const int token = qt * 64 + wave * 16 + l16;
        bf16* orow = Ob + (size_t)(b * cS + token) * (cNH * cHD) + h * cHD;
        #pragma unroll
        for (int dt = 0; dt < 8; ++dt) {
            bf16x4 o4;
            #pragma unroll
            for (int r = 0; r < 4; ++r) o4[r] = (bf16)(oac[dt][r] * inv);
            *(bf16x4*)&orow[dt * 16 + quad * 4] = o4;
        }
    }
}

extern "C" void kernel_launch(void* const* d_in, const int* in_sizes, int n_in,
                              void* d_out, int out_size, void* d_ws, size_t ws_size,
                              hipStream_t stream) {
    const float* x    = (const float*)d_in[0];
    const float* cosb = (const float*)d_in[1];
    const float* sinb = (const float*)d_in[2];
    // d_in[3] = attention_mask (exactly causal NEG) — implemented analytically
    const float* qw = (const float*)d_in[4];
    const float* kw = (const float*)d_in[5];
    const float* vw = (const float*)d_in[6];
    const float* qb = (const float*)d_in[7];
    const float* kb_ = (const float*)d_in[8];
    const float* vb = (const float*)d_in[9];
    const float* qA = (const float*)d_in[10];
    const float* qB = (const float*)d_in[11];
    const float* kA = (const float*)d_in[12];
    const float* kB = (const float*)d_in[13];
    const float* vA = (const float*)d_in[14];
    const float* vB = (const float*)d_in[15];
    const float* ow = (const float*)d_in[16];
    float* out = (float*)d_out;

    char* ws = (char*)d_ws;
    bf16* Xbf   = (bf16*)ws;  ws += (size_t)cNTOK * cH * 2;            // 16.8 MB
    bf16* Wc    = (bf16*)ws;  ws += (size_t)cNQKV * cH * 2;            // 12.6 MB
    float* biasc = (float*)ws; ws += (size_t)cNQKV * 4;                // 12 KB
    bf16* Qr    = (bf16*)ws;  ws += (size_t)cB * cNH * cS * cHD * 2;   // 16.8 MB
    bf16* Kr    = (bf16*)ws;  ws += (size_t)cB * cKVH * cS * cHD * 2;  // 4.2 MB
    bf16* Vt    = (bf16*)ws;  ws += (size_t)cB * cKVH * cHD * cS * 2;  // 4.2 MB
    bf16* OWbf  = (bf16*)ws;  ws += (size_t)cH * cH * 2;               // 8.4 MB
    bf16* Aout  = (bf16*)ws;  ws += (size_t)cNTOK * cQD * 2;           // 16.8 MB

    prep_all<<<15360, 256, 0, stream>>>(x, Xbf, ow, OWbf, qw, kw, vw, qA, qB, kA, kB, vA, vB,
                                        qb, kb_, vb, Wc, biasc);

    gemm_qkv5<<<dim3(cNQKV / 128, cNTOK / 128), 256, 0, stream>>>(Xbf, Wc, biasc, cosb, sinb, Qr, Kr, Vt);

    flash7<<<dim3(16, cNH, cB), 256, 0, stream>>>(Qr, Kr, Vt, Aout);

    gemm_oproj5<<<dim3(cH / 128, cNTOK / 128), 256, 0, stream>>>(Aout, OWbf, out);
}

// Round 9
// 361.527 us; speedup vs baseline: 1.2570x; 1.2570x over previous
//
#include <hip/hip_runtime.h>

// Problem constants
constexpr int cB   = 2;
constexpr int cS   = 2048;
constexpr int cH   = 2048;
constexpr int cNH  = 16;
constexpr int cKVH = 4;
constexpr int cHD  = 128;
constexpr int cQD  = 2048;   // NH*HD
constexpr int cKVD = 512;    // KVH*HD
constexpr int cNQKV = 3072;  // QD + 2*KVD
constexpr int cNTOK = 4096;  // B*S
#define ATTN_SCALE 0.08838834764831845f
// ATTN_SCALE * log2(e): Q pre-scaled so softmax runs in exp2 domain
#define QSCALE 0.12751589549581288f

typedef __bf16 bf16;
typedef __attribute__((ext_vector_type(8))) __bf16 bf16x8;
typedef __attribute__((ext_vector_type(4))) __bf16 bf16x4;
typedef __attribute__((ext_vector_type(4))) float  f32x4;

__device__ __forceinline__ void async_load16(const bf16* g, bf16* l) {
    __builtin_amdgcn_global_load_lds(
        (const __attribute__((address_space(1))) void*)g,
        (__attribute__((address_space(3))) void*)l, 16, 0, 0);
}

// ---------------- fused prep: x->bf16, ow->bf16, LoRA-folded QKV weight (1 kernel, 3 jobs) ----------
__global__ __launch_bounds__(256) void prep_all(
        const float* __restrict__ x, bf16* __restrict__ Xbf,
        const float* __restrict__ ow, bf16* __restrict__ OWbf,
        const float* __restrict__ qw, const float* __restrict__ kw, const float* __restrict__ vw,
        const float* __restrict__ qA, const float* __restrict__ qB,
        const float* __restrict__ kA, const float* __restrict__ kB,
        const float* __restrict__ vA, const float* __restrict__ vB,
        const float* __restrict__ qb, const float* __restrict__ kbias, const float* __restrict__ vb,
        bf16* __restrict__ Wc, float* __restrict__ biasc) {
    const int bid = blockIdx.x;
    if (bid < 8192) {                    // x -> Xbf
        const int i = (bid * 256 + threadIdx.x) * 4;
        f32x4 v = *(const f32x4*)(x + i);
        bf16x4 o;
        o[0] = (bf16)v[0]; o[1] = (bf16)v[1]; o[2] = (bf16)v[2]; o[3] = (bf16)v[3];
        *(bf16x4*)(Xbf + i) = o;
        return;
    }
    if (bid < 12288) {                   // ow -> OWbf
        const int i = ((bid - 8192) * 256 + threadIdx.x) * 4;
        f32x4 v = *(const f32x4*)(ow + i);
        bf16x4 o;
        o[0] = (bf16)v[0]; o[1] = (bf16)v[1]; o[2] = (bf16)v[2]; o[3] = (bf16)v[3];
        *(bf16x4*)(OWbf + i) = o;
        return;
    }
    // LoRA fold
    const int pb = bid - 12288;
    const int bx = pb & 3, by = pb >> 2;
    const int wave = threadIdx.x >> 6, lane = threadIdx.x & 63;
    const int n = by * 4 + wave;
    const int k0 = bx * 512 + lane * 8;
    const float* W; const float* Am; const float* Bm; const float* bias; int nn, nd;
    if (n < cQD)             { W = qw; Am = qA; Bm = qB; bias = qb;    nn = n;               nd = cQD; }
    else if (n < cQD + cKVD) { W = kw; Am = kA; Bm = kB; bias = kbias; nn = n - cQD;         nd = cKVD; }
    else                     { W = vw; Am = vA; Bm = vB; bias = vb;    nn = n - cQD - cKVD;  nd = cKVD; }
    if (bx == 0 && lane == 0) biasc[n] = bias[nn];
    float bm[16];
    #pragma unroll
    for (int r = 0; r < 16; ++r) bm[r] = Bm[r * nd + nn];
    const float* wrow = W + (size_t)nn * cH + k0;
    f32x4 w0 = *(const f32x4*)(wrow);
    f32x4 w1 = *(const f32x4*)(wrow + 4);
    bf16x8 o;
    #pragma unroll
    for (int j = 0; j < 8; ++j) {
        const f32x4* am = (const f32x4*)(Am + (size_t)(k0 + j) * 16);
        f32x4 a0 = am[0], a1 = am[1], a2 = am[2], a3 = am[3];
        float acc = 0.f;
        #pragma unroll
        for (int c = 0; c < 4; ++c) acc += a0[c] * bm[c] + a1[c] * bm[4 + c]
                                         + a2[c] * bm[8 + c] + a3[c] * bm[12 + c];
        const float wv = (j < 4) ? w0[j] : w1[j - 4];
        o[j] = (bf16)(wv + 2.0f * acc);
    }
    *(bf16x8*)&Wc[(size_t)n * cH + k0] = o;
}

// ---------------- QKV GEMM v6: 256x128 tile, BK=64, 8 waves (4Mx2N), single-buffer 48 KiB ----------
// Staged-bytes model: bytes = M*N*K*2*(1/BM+1/BN); 256x128 -> 604 MB (-25% vs 128^2).
// Per-wave 64x64 acc[4][4] + epilogue = verified qkv4 structure (wr->wm, wc->wn).
// 8-chunk row swizzle (measured 0 bank conflicts in r6). 2 blocks/CU via launch_bounds(512,4).
__global__ __launch_bounds__(512, 4) void gemm_qkv6(const bf16* __restrict__ A, const bf16* __restrict__ Bw,
                                                    const float* __restrict__ bias,
                                                    const float* __restrict__ cosb, const float* __restrict__ sinb,
                                                    bf16* __restrict__ Qr, bf16* __restrict__ Kr,
                                                    bf16* __restrict__ Vt) {
    __shared__ bf16 Al[256 * 64];   // 32 KiB
    __shared__ bf16 Bl[128 * 64];   // 16 KiB -> 48 KiB total
    const int tid = threadIdx.x;
    const int wave = tid >> 6, lane = tid & 63;
    const int quad = lane >> 4, l16 = lane & 15;
    const int wm = wave >> 1, wn = wave & 1;   // 4 M-waves x 2 N-waves
    const int K = cH;
    constexpr int GX = cNQKV / 128;            // 24 (N)
    constexpr int NWG = GX * (cNTOK / 256);    // 384, %8==0 -> bijective XCD swizzle

    const int orig = blockIdx.y * GX + blockIdx.x;
    const int swz = (orig & 7) * (NWG >> 3) + (orig >> 3);
    const long bm = (long)(swz / GX) * 256;
    const long bn = (long)(swz % GX) * 128;

    f32x4 acc[4][4];
    #pragma unroll
    for (int i = 0; i < 4; ++i)
        #pragma unroll
        for (int c = 0; c < 4; ++c) acc[i][c] = f32x4{0.f, 0.f, 0.f, 0.f};

    // staging (8-chunk row swizzle, conflict-free): slot si=(row, c8); global chunk c8^(row&7)
    int aago[4], aslo[4], bgo[2], bslo[2];
    #pragma unroll
    for (int i2 = 0; i2 < 4; ++i2) {
        const int si = i2 * 512 + tid;        // 0..2047, rows 0..255
        const int row = si >> 3, c8 = si & 7;
        aago[i2] = row * K + (c8 ^ (row & 7)) * 8;
        aslo[i2] = si * 8;
    }
    #pragma unroll
    for (int i2 = 0; i2 < 2; ++i2) {
        const int si = i2 * 512 + tid;        // 0..1023, rows 0..127
        const int row = si >> 3, c8 = si & 7;
        bgo[i2] = row * K + (c8 ^ (row & 7)) * 8;
        bslo[i2] = si * 8;
    }
    const size_t bmK = (size_t)bm * K, bnK = (size_t)bn * K;

    auto STAGE = [&](int tt) {
        const bf16* As_ = A  + bmK + (size_t)tt * 64;
        const bf16* Bs_ = Bw + bnK + (size_t)tt * 64;
        #pragma unroll
        for (int i2 = 0; i2 < 4; ++i2) async_load16(As_ + aago[i2], &Al[aslo[i2]]);
        #pragma unroll
        for (int i2 = 0; i2 < 2; ++i2) async_load16(Bs_ + bgo[i2], &Bl[bslo[i2]]);
    };

    constexpr int NT = cH / 64;   // 32
    STAGE(0);
    const int sw = l16 & 7;

    for (int t = 0; t < NT; ++t) {
        asm volatile("s_waitcnt vmcnt(0)" ::: "memory");
        __builtin_amdgcn_s_barrier();
        #pragma unroll
        for (int ks = 0; ks < 2; ++ks) {
            const int g = ks * 4 + quad;          // k-chunk 0..7
            const int cofs = (g ^ sw) * 8;
            bf16x8 af[4], bfr[4];
            #pragma unroll
            for (int i = 0; i < 4; ++i)
                af[i] = *(const bf16x8*)&Al[(wm * 64 + i * 16 + l16) * 64 + cofs];
            #pragma unroll
            for (int c = 0; c < 4; ++c) {
                const int nrow = wn * 32 + (c & 1) * 16 + (c >> 1) * 64 + l16;
                bfr[c] = *(const bf16x8*)&Bl[nrow * 64 + cofs];
            }
            __builtin_amdgcn_s_setprio(1);
            #pragma unroll
            for (int i = 0; i < 4; ++i)
                #pragma unroll
                for (int c = 0; c < 4; ++c)
                    acc[i][c] = __builtin_amdgcn_mfma_f32_16x16x32_bf16(af[i], bfr[c], acc[i][c], 0, 0, 0);
            __builtin_amdgcn_s_setprio(0);
        }
        asm volatile("s_waitcnt lgkmcnt(0)" ::: "memory");
        __builtin_amdgcn_s_barrier();
        if (t + 1 < NT) STAGE(t + 1);
    }

    // ---- epilogue (verified qkv4 structure; wr->wm, wc->wn): bias + RoPE + reorder + V-transpose ----
    #pragma unroll
    for (int c = 0; c < 4; ++c) {
        const int nloc = wn * 32 + (c & 1) * 16 + (c >> 1) * 64 + l16;
        const float bv = bias[bn + nloc];
        #pragma unroll
        for (int i = 0; i < 4; ++i)
            #pragma unroll
            for (int r = 0; r < 4; ++r) acc[i][c][r] += bv;
    }

    const int head = (int)(bn >> 7);   // 0..23: 16 Q, 4 K, 4 V
    if (head < cNH + cKVH) {
        const bool isQ = head < cNH;
        #pragma unroll
        for (int cl = 0; cl < 2; ++cl) {
            const int d = wn * 32 + cl * 16 + l16;   // 0..63, pair at d+64 in frag cl+2
            #pragma unroll
            for (int i = 0; i < 4; ++i)
                #pragma unroll
                for (int r = 0; r < 4; ++r) {
                    const long t = bm + wm * 64 + i * 16 + quad * 4 + r;
                    const float cv = cosb[t * cHD + d];
                    const float sv = sinb[t * cHD + d];
                    const float v1 = acc[i][cl][r], v2 = acc[i][cl + 2][r];
                    float o1 = v1 * cv - v2 * sv;
                    float o2 = v2 * cv + v1 * sv;
                    if (isQ) { o1 *= QSCALE; o2 *= QSCALE; }
                    const int b = (int)(t >> 11), s = (int)(t & 2047);
                    bf16* dst = isQ
                        ? Qr + ((size_t)(b * cNH + head) * cS + s) * cHD
                        : Kr + ((size_t)(b * cKVH + (head - cNH)) * cS + s) * cHD;
                    dst[d]      = (bf16)o1;
                    dst[d + 64] = (bf16)o2;
                }
        }
    } else {
        const int kv = head - cNH - cKVH;
        const int b = (int)(bm >> 11);
        const int sbase = (int)(bm & 2047);
        #pragma unroll
        for (int c = 0; c < 4; ++c) {
            const int d = wn * 32 + (c & 1) * 16 + (c >> 1) * 64 + l16;
            #pragma unroll
            for (int i = 0; i < 4; ++i) {
                const int s0 = sbase + wm * 64 + i * 16 + quad * 4;
                bf16x4 o4;
                #pragma unroll
                for (int r = 0; r < 4; ++r) o4[r] = (bf16)acc[i][c][r];
                *(bf16x4*)&Vt[((size_t)((b * cKVH + kv) * cHD) + d) * cS + s0] = o4;
            }
        }
    }
}

// ---------------- o-proj GEMM v5 (round-7 verified, unchanged) ----------------
__global__ __launch_bounds__(256, 2) void gemm_oproj5(const bf16* __restrict__ A, const bf16* __restrict__ Bw,
                                                      float* __restrict__ Cp) {
    __shared__ bf16 Al[128 * 128];   // 32 KiB
    __shared__ bf16 Bl[128 * 128];   // 32 KiB
    const int tid = threadIdx.x;
    const int wave = tid >> 6, lane = tid & 63;
    const int quad = lane >> 4, l16 = lane & 15;
    const int wr = wave >> 1, wc = wave & 1;
    constexpr int K = cH, N = cH;
    constexpr int GX = cH / 128;               // 16
    constexpr int NWG = GX * (cNTOK / 128);    // 512, %8==0

    const int orig = blockIdx.y * GX + blockIdx.x;
    const int swz = (orig & 7) * (NWG >> 3) + (orig >> 3);
    const long bm = (long)(swz / GX) * 128;
    const long bn = (long)(swz % GX) * 128;

    f32x4 acc[4][4];
    #pragma unroll
    for (int i = 0; i < 4; ++i)
        #pragma unroll
        for (int c = 0; c < 4; ++c) acc[i][c] = f32x4{0.f, 0.f, 0.f, 0.f};

    int ago[8], slo[8];
    #pragma unroll
    for (int i2 = 0; i2 < 8; ++i2) {
        const int si = i2 * 256 + tid;
        const int row = si >> 4, c16 = si & 15;
        const int csw = (c16 & 8) | ((c16 & 7) ^ (row & 7));
        ago[i2] = row * K + csw * 8;
        slo[i2] = si * 8;
    }
    const size_t bmK = (size_t)bm * K, bnK = (size_t)bn * K;

    auto STAGE = [&](int tt) {
        const bf16* As_ = A  + bmK + (size_t)tt * 128;
        const bf16* Bs_ = Bw + bnK + (size_t)tt * 128;
        #pragma unroll
        for (int i2 = 0; i2 < 8; ++i2) {
            async_load16(As_ + ago[i2], &Al[slo[i2]]);
            async_load16(Bs_ + ago[i2], &Bl[slo[i2]]);
        }
    };

    constexpr int NT = K / 128;   // 16
    STAGE(0);
    const int sw = l16 & 7;

    for (int t = 0; t < NT; ++t) {
        asm volatile("s_waitcnt vmcnt(0)" ::: "memory");
        __builtin_amdgcn_s_barrier();
        #pragma unroll
        for (int ks = 0; ks < 4; ++ks) {
            const int g = ks * 4 + quad;
            const int gsw = (g & 8) | ((g & 7) ^ sw);
            const int cofs = gsw * 8;
            bf16x8 af[4], bfr[4];
            #pragma unroll
            for (int i = 0; i < 4; ++i)
                af[i] = *(const bf16x8*)&Al[(wr * 64 + i * 16 + l16) * 128 + cofs];
            #pragma unroll
            for (int c = 0; c < 4; ++c)
                bfr[c] = *(const bf16x8*)&Bl[(wc * 64 + c * 16 + l16) * 128 + cofs];
            __builtin_amdgcn_s_setprio(1);
            #pragma unroll
            for (int i = 0; i < 4; ++i)
                #pragma unroll
                for (int c = 0; c < 4; ++c)
                    acc[i][c] = __builtin_amdgcn_mfma_f32_16x16x32_bf16(af[i], bfr[c], acc[i][c], 0, 0, 0);
            __builtin_amdgcn_s_setprio(0);
        }
        asm volatile("s_waitcnt lgkmcnt(0)" ::: "memory");
        __builtin_amdgcn_s_barrier();
        if (t + 1 < NT) STAGE(t + 1);
    }

    #pragma unroll
    for (int i = 0; i < 4; ++i)
        #pragma unroll
        for (int c = 0; c < 4; ++c) {
            const long m0 = bm + wr * 64 + i * 16 + quad * 4;
            const long n  = bn + wc * 64 + c * 16 + l16;
            #pragma unroll
            for (int r = 0; r < 4; ++r)
                Cp[(m0 + r) * N + n] = acc[i][c][r];
        }
}

// ---------------- flash attention v6 (round-7 verified, restored): KVBLK=128, K+V LDS-staged ----
__global__ __launch_bounds__(256, 2) void flash6(const bf16* __restrict__ Q, const bf16* __restrict__ K,
                                                 const bf16* __restrict__ Vt, bf16* __restrict__ Ob) {
    __shared__ bf16 kb[128 * 128];   // 32 KiB  (kpos rows x d cols)
    __shared__ bf16 vb[128 * 128];   // 32 KiB  (d rows x kpos cols)
    __shared__ bf16 pb[4 * 2048];    // 16 KiB  -> 80 KiB total, 2 blocks/CU
    const int tid = threadIdx.x;
    const int wave = tid >> 6, lane = tid & 63;
    const int quad = lane >> 4, l16 = lane & 15;
    const int pi = blockIdx.x;               // 0..15
    const int h = blockIdx.y, b = blockIdx.z;

    const bf16* Qh = Q  + (size_t)(b * cNH + h) * cS * cHD;
    const bf16* Kg = K  + (size_t)(b * cKVH + (h >> 2)) * cS * cHD;
    const bf16* Vg = Vt + (size_t)(b * cKVH + (h >> 2)) * cHD * cS;

    int kgo[8], vgo[8], slo[8];
    #pragma unroll
    for (int i2 = 0; i2 < 8; ++i2) {
        const int si = i2 * 256 + tid;       // 0..2047
        const int row = si >> 4, c16 = si & 15;
        const int csw = (c16 & 8) | ((c16 & 7) ^ (row & 7));
        kgo[i2] = row * cHD + csw * 8;       // K: kpos-row x d-chunk
        vgo[i2] = row * cS  + csw * 8;       // V: d-row x s-chunk
        slo[i2] = si * 8;
    }

    #pragma unroll
    for (int t2 = 0; t2 < 2; ++t2) {
        const int qt = t2 == 0 ? (31 - pi) : pi;

        const bf16* Qg = Qh + (size_t)qt * 64 * cHD;
        bf16x8 qf[4];
        #pragma unroll
        for (int ks = 0; ks < 4; ++ks)
            qf[ks] = *(const bf16x8*)(Qg + (size_t)(wave * 16 + l16) * cHD + ks * 32 + quad * 8);

        f32x4 oac[8];
        #pragma unroll
        for (int dt = 0; dt < 8; ++dt) oac[dt] = f32x4{0.f, 0.f, 0.f, 0.f};
        float m_ = -3.0e38f, l_ = 0.f;

        const int nkt = (qt >> 1) + 1;       // 128-wide tiles covering [0, qt*64+63]
        for (int kt = 0; kt < nkt; ++kt) {
            __syncthreads();                 // prior-step reads sealed before overwrite
            const bf16* Kt  = Kg + (size_t)kt * 128 * cHD;
            const bf16* Vtt = Vg + kt * 128;
            #pragma unroll
            for (int i2 = 0; i2 < 8; ++i2) async_load16(Kt + kgo[i2], kb + slo[i2]);
            #pragma unroll
            for (int i2 = 0; i2 < 8; ++i2) async_load16(Vtt + vgo[i2], vb + slo[i2]);
            __syncthreads();                 // drains vmcnt(0): tile visible

            // S^T = K Q^T : st[mt] rows = kpos (mt*16+quad*4+r), cols = q (l16)
            f32x4 st[8];
            #pragma unroll
            for (int mt = 0; mt < 8; ++mt) {
                bf16x8 kf[4];
                #pragma unroll
                for (int ks = 0; ks < 4; ++ks) {
                    const int c = ks * 4 + quad;
                    const int csw = (c & 8) | ((c & 7) ^ (l16 & 7));
                    kf[ks] = *(const bf16x8*)&kb[(mt * 16 + l16) * 128 + csw * 8];
                }
                f32x4 a = f32x4{0.f, 0.f, 0.f, 0.f};
                __builtin_amdgcn_s_setprio(1);
                #pragma unroll
                for (int ks = 0; ks < 4; ++ks)
                    a = __builtin_amdgcn_mfma_f32_16x16x32_bf16(kf[ks], qf[ks], a, 0, 0, 0);
                __builtin_amdgcn_s_setprio(0);
                st[mt] = a;
            }

            // causal mask + online softmax (exp2 domain; lane l16 = q row)
            const int qpos = qt * 64 + wave * 16 + l16;
            float tmax = -3.0e38f;
            if ((kt * 128 + 127) > (qt * 64 + wave * 16)) {
                #pragma unroll
                for (int mt = 0; mt < 8; ++mt)
                    #pragma unroll
                    for (int r = 0; r < 4; ++r) {
                        const int kpos = kt * 128 + mt * 16 + quad * 4 + r;
                        if (kpos > qpos) st[mt][r] = -3.0e38f;
                        tmax = fmaxf(tmax, st[mt][r]);
                    }
            } else {
                #pragma unroll
                for (int mt = 0; mt < 8; ++mt)
                    #pragma unroll
                    for (int r = 0; r < 4; ++r) tmax = fmaxf(tmax, st[mt][r]);
            }
            tmax = fmaxf(tmax, __shfl_xor(tmax, 16, 64));
            tmax = fmaxf(tmax, __shfl_xor(tmax, 32, 64));
            const float mnew = fmaxf(m_, tmax);
            if (__any(tmax > m_)) {
                const float alpha = __builtin_amdgcn_exp2f(m_ - mnew);
                l_ *= alpha;
                #pragma unroll
                for (int dt = 0; dt < 8; ++dt)
                    #pragma unroll
                    for (int r = 0; r < 4; ++r) oac[dt][r] *= alpha;
            }
            m_ = mnew;
            float rs = 0.f;
            #pragma unroll
            for (int mt = 0; mt < 8; ++mt)
                #pragma unroll
                for (int r = 0; r < 4; ++r) {
                    const float p = __builtin_amdgcn_exp2f(st[mt][r] - mnew);
                    st[mt][r] = p;
                    rs += p;
                }
            rs += __shfl_xor(rs, 16, 64);
            rs += __shfl_xor(rs, 32, 64);
            l_ += rs;

            // P write into per-wave pb region (wave-private, no barrier)
            #pragma unroll
            for (int mt = 0; mt < 8; ++mt) {
                bf16x4 p4;
                #pragma unroll
                for (int r = 0; r < 4; ++r) p4[r] = (bf16)st[mt][r];
                const int c16 = mt * 2 + (quad >> 1);
                const int csw = (c16 & 8) | ((c16 & 7) ^ (l16 & 7));
                *(bf16x4*)&pb[wave * 2048 + l16 * 128 + csw * 8 + (quad & 1) * 4] = p4;
            }

            // O^T += V^T P^T  (K-dim = 128 kpos = 4 ks)
            bf16x8 pf[4];
            #pragma unroll
            for (int ks = 0; ks < 4; ++ks) {
                const int c = ks * 4 + quad;
                const int csw = (c & 8) | ((c & 7) ^ (l16 & 7));
                pf[ks] = *(const bf16x8*)&pb[wave * 2048 + l16 * 128 + csw * 8];
            }
            #pragma unroll
            for (int dt = 0; dt < 8; ++dt) {
                bf16x8 vf[4];
                #pragma unroll
                for (int ks = 0; ks < 4; ++ks) {
                    const int c = ks * 4 + quad;
                    const int csw = (c & 8) | ((c & 7) ^ (l16 & 7));
                    vf[ks] = *(const bf16x8*)&vb[(dt * 16 + l16) * 128 + csw * 8];
                }
                __builtin_amdgcn_s_setprio(1);
                #pragma unroll
                for (int ks = 0; ks < 4; ++ks)
                    oac[dt] = __builtin_amdgcn_mfma_f32_16x16x32_bf16(vf[ks], pf[ks], oac[dt], 0, 0, 0);
                __builtin_amdgcn_s_setprio(0);
            }
        }

        // epilogue: lane l16 = token, regs = d contiguous -> b64 stores
        const float inv = 1.0f / l_;
        const int token = qt * 64 + wave * 16 + l16;
        bf16* orow = Ob + (size_t)(b * cS + token) * (cNH * cHD) + h * cHD;
        #pragma unroll
        for (int dt = 0; dt < 8; ++dt) {
            bf16x4 o4;
            #pragma unroll
            for (int r = 0; r < 4; ++r) o4[r] = (bf16)(oac[dt][r] * inv);
            *(bf16x4*)&orow[dt * 16 + quad * 4] = o4;
        }
    }
}

extern "C" void kernel_launch(void* const* d_in, const int* in_sizes, int n_in,
                              void* d_out, int out_size, void* d_ws, size_t ws_size,
                              hipStream_t stream) {
    const float* x    = (const float*)d_in[0];
    const float* cosb = (const float*)d_in[1];
    const float* sinb = (const float*)d_in[2];
    // d_in[3] = attention_mask (exactly causal NEG) — implemented analytically
    const float* qw = (const float*)d_in[4];
    const float* kw = (const float*)d_in[5];
    const float* vw = (const float*)d_in[6];
    const float* qb = (const float*)d_in[7];
    const float* kb_ = (const float*)d_in[8];
    const float* vb = (const float*)d_in[9];
    const float* qA = (const float*)d_in[10];
    const float* qB = (const float*)d_in[11];
    const float* kA = (const float*)d_in[12];
    const float* kB = (const float*)d_in[13];
    const float* vA = (const float*)d_in[14];
    const float* vB = (const float*)d_in[15];
    const float* ow = (const float*)d_in[16];
    float* out = (float*)d_out;

    char* ws = (char*)d_ws;
    bf16* Xbf   = (bf16*)ws;  ws += (size_t)cNTOK * cH * 2;            // 16.8 MB
    bf16* Wc    = (bf16*)ws;  ws += (size_t)cNQKV * cH * 2;            // 12.6 MB
    float* biasc = (float*)ws; ws += (size_t)cNQKV * 4;                // 12 KB
    bf16* Qr    = (bf16*)ws;  ws += (size_t)cB * cNH * cS * cHD * 2;   // 16.8 MB
    bf16* Kr    = (bf16*)ws;  ws += (size_t)cB * cKVH * cS * cHD * 2;  // 4.2 MB
    bf16* Vt    = (bf16*)ws;  ws += (size_t)cB * cKVH * cHD * cS * 2;  // 4.2 MB
    bf16* OWbf  = (bf16*)ws;  ws += (size_t)cH * cH * 2;               // 8.4 MB
    bf16* Aout  = (bf16*)ws;  ws += (size_t)cNTOK * cQD * 2;           // 16.8 MB

    prep_all<<<15360, 256, 0, stream>>>(x, Xbf, ow, OWbf, qw, kw, vw, qA, qB, kA, kB, vA, vB,
                                        qb, kb_, vb, Wc, biasc);

    gemm_qkv6<<<dim3(cNQKV / 128, cNTOK / 256), 512, 0, stream>>>(Xbf, Wc, biasc, cosb, sinb, Qr, Kr, Vt);

    flash6<<<dim3(16, cNH, cB), 256, 0, stream>>>(Qr, Kr, Vt, Aout);

    gemm_oproj5<<<dim3(cH / 128, cNTOK / 128), 256, 0, stream>>>(Aout, OWbf, out);
}